// Round 6
// baseline (108.113 us; speedup 1.0000x reference)
//
#include <hip/hip_runtime.h>

#define GS    7
#define CCH   490
#define HH    128
#define HHF   64        // rows per half-block
#define WW    128
#define LDW   132       // padded LDS row stride (dwords)
#define NB    2
#define NCH   (NB * CCH)
#define NOUT  (512 * CCH)

// Half-image SAT blocks: 33.8KB LDS -> 4 blocks/CU = 32 waves/CU (full occupancy).
// Each (channel, half) block builds the local SAT of its 64x128 slab and
// atomically adds its clipped-rectangle partial (already divided by the full
// area) into out. out is zero-initialized by a memset node; fp32 add is
// commutative, so the two-way atomic merge is bitwise deterministic.
__global__ __launch_bounds__(512, 8) void psroi_half(
    const float* __restrict__ rois,
    const float* __restrict__ feat,
    const int*   __restrict__ stride_p,
    float*       __restrict__ out)
{
#pragma clang fp contract(off)
    __shared__ float S[HHF * LDW];   // 33,792 B local SAT
    __shared__ float T[4 * 128];     // seg-total exchange

    const int ch = blockIdx.x >> 1;  // channel (b*490+c)
    const int h  = blockIdx.x & 1;   // 0 = rows 0..63, 1 = rows 64..127
    const int tid = threadIdx.x;

    // ---- Phase A: cumsum over H within the half. thread = (col, 16-row seg) ----
    {
        const int col = tid & 127;
        const int seg = tid >> 7;        // 0..3, uniform per wave
        const int r0  = seg * 16;
        const float* __restrict__ fp =
            feat + (size_t)ch * (HH * WW) + (h * HHF + r0) * WW + col;

        float v[16];
        #pragma unroll
        for (int i = 0; i < 16; ++i)     // coalesced 256B wave-loads
            v[i] = fp[i * WW];
        #pragma unroll
        for (int i = 1; i < 16; ++i)     // serial register scan
            v[i] += v[i - 1];

        T[seg * 128 + col] = v[15];
        __syncthreads();
        float offA = 0.0f;
        if (seg > 0) offA += T[0 * 128 + col];
        if (seg > 1) offA += T[1 * 128 + col];
        if (seg > 2) offA += T[2 * 128 + col];

        float* sp = &S[r0 * LDW + col];
        #pragma unroll
        for (int i = 0; i < 16; ++i)     // b32 writes, 2-way banks (free)
            sp[i * LDW] = v[i] + offA;
    }
    __syncthreads();

    // ---- Phase B: cumsum over W. thread = (row 0..63, 16-col seg 0..7) ----
    {
        const int row = tid >> 3;
        const int ws_ = tid & 7;
        float* rp = &S[row * LDW + ws_ * 16];

        float u[16];
        #pragma unroll
        for (int i = 0; i < 4; ++i) {    // 4x ds_read_b128, bank-balanced
            const float4 q = *(const float4*)&rp[i * 4];
            u[4 * i + 0] = q.x; u[4 * i + 1] = q.y;
            u[4 * i + 2] = q.z; u[4 * i + 3] = q.w;
        }
        #pragma unroll
        for (int i = 1; i < 16; ++i)
            u[i] += u[i - 1];

        // exclusive prefix of seg totals across the 8 lanes of each row group
        float s = u[15];
        float t;
        t = __shfl_up(s, 1, 64); if ((tid & 7) >= 1) s += t;
        t = __shfl_up(s, 2, 64); if ((tid & 7) >= 2) s += t;
        t = __shfl_up(s, 4, 64); if ((tid & 7) >= 4) s += t;
        float offB = __shfl_up(s, 1, 64);
        if ((tid & 7) == 0) offB = 0.0f;

        #pragma unroll
        for (int i = 0; i < 4; ++i) {    // 4x ds_write_b128 in place
            float4 q;
            q.x = u[4 * i + 0] + offB; q.y = u[4 * i + 1] + offB;
            q.z = u[4 * i + 2] + offB; q.w = u[4 * i + 3] + offB;
            *(float4*)&rp[i * 4] = q;
        }
    }
    __syncthreads();

    // ---- Pooling: thread n = roi n; clip rows to this half, use LOCAL SAT ----
    {
        const int n   = tid;
        const int b   = ch / CCH;
        const int c   = ch - b * CCH;
        const int bi  = (int)rois[n * 5 + 0];
        if (bi == b) {
            const float ss = 1.0f / (float)(*stride_p);
            const float x1 = rois[n * 5 + 1];
            const float y1 = rois[n * 5 + 2];
            const float x2 = rois[n * 5 + 3];
            const float y2 = rois[n * 5 + 4];

            // exact reference op order, fp32, no contraction
            float rsw = rintf(x1) * ss;
            float rsh = rintf(y1) * ss;
            float rew = (rintf(x2) + 1.0f) * ss;
            float reh = (rintf(y2) + 1.0f) * ss;
            float rwm = (rew - rsw) * 1.3f;
            float rhm = (reh - rsh) * 1.3f;
            const float swm = (rsw + rew) * 0.5f - rwm * 0.5f;
            const float shm = (rsh + reh) * 0.5f - rhm * 0.5f;
            rwm = fmaxf(rwm, 0.1f);
            rhm = fmaxf(rhm, 0.1f);
            const float bin_h = rhm / 7.0f;
            const float bin_w = rwm / 7.0f;
            const float dh = bin_h * 0.25f;
            const float dw = bin_w * 0.25f;

            const int d   = c / (GS * GS);
            const int rem = c - d * (GS * GS);
            const int pi  = rem / GS;
            const int pj  = rem - pi * GS;
            const float gi = (float)pi;
            const float gj = (float)pj;

            const int hs  = (int)fminf(fmaxf(floorf(shm + gi * bin_h - dh),          0.0f), 128.0f);
            const int he  = (int)fminf(fmaxf(ceilf (shm + (gi + 1.0f) * bin_h + dh), 0.0f), 128.0f);
            const int ws2 = (int)fminf(fmaxf(floorf(swm + gj * bin_w - dw),          0.0f), 128.0f);
            const int we  = (int)fminf(fmaxf(ceilf (swm + (gj + 1.0f) * bin_w + dw), 0.0f), 128.0f);

            const int area = (he - hs) * (we - ws2);
            // clip row range to this half's local coordinates [0,64)
            const int ls = min(max(hs - h * HHF, 0), HHF);
            const int le = min(max(he - h * HHF, 0), HHF);

            if (area > 0 && le > ls && we > ws2) {
                const float A  =              S[(le - 1) * LDW + (we  - 1)];
                const float Bv = (ls  > 0) ?  S[(ls - 1) * LDW + (we  - 1)] : 0.0f;
                const float Cv = (ws2 > 0) ?  S[(le - 1) * LDW + (ws2 - 1)] : 0.0f;
                const float Dv = (ls > 0 && ws2 > 0) ? S[(ls - 1) * LDW + (ws2 - 1)] : 0.0f;
                const float partial = ((A - Bv) - Cv) + Dv;
                atomicAdd(&out[(size_t)n * CCH + c], partial / (float)area);
            }
        }
    }
}

extern "C" void kernel_launch(void* const* d_in, const int* in_sizes, int n_in,
                              void* d_out, int out_size, void* d_ws, size_t ws_size,
                              hipStream_t stream)
{
    const float* rois     = (const float*)d_in[0];
    const float* feat     = (const float*)d_in[1];
    const int*   stride_p = (const int*)d_in[2];
    float*       out      = (float*)d_out;

    // zero-init output (capture-safe memset node); halves atomically accumulate
    hipMemsetAsync(d_out, 0, (size_t)out_size * sizeof(float), stream);

    dim3 grid(NCH * 2);   // (channel, half) blocks: 1960, 4/CU resident
    dim3 block(512);
    hipLaunchKernelGGL(psroi_half, grid, block, 0, stream, rois, feat, stride_p, out);
}

// Round 7
// 99.447 us; speedup vs baseline: 1.0871x; 1.0871x over previous
//
#include <hip/hip_runtime.h>

#define GS   7
#define CCH  490
#define HH   128
#define WW   128
#define LDW  132        // padded row stride: 132 mod 32 = 4 spreads rows across banks
#define NB   2
#define NCH  (NB * CCH)

// One block per (batch,channel). Build only the ROW prefix (cumsum along W)
// in LDS — bins are short (1..12 rows), so pooling sums rowpfx differences.
// Single barrier per block; no column scan, no atomics, every output element
// written exactly once.
__global__ __launch_bounds__(512, 4) void psroi_rowpfx(
    const float* __restrict__ rois,
    const float* __restrict__ feat,
    const int*   __restrict__ stride_p,
    float*       __restrict__ out)
{
#pragma clang fp contract(off)
    __shared__ float S[HH * LDW];   // 67,584 B -> 2 blocks/CU

    const int ch  = blockIdx.x;     // b*490 + c
    const int tid = threadIdx.x;

    // ---- Phase 1: load + cumsum along W (register scan), no internal barrier ----
    {
        const int row = tid >> 2;   // 0..127; quad of lanes shares a row
        const int sg  = tid & 3;    // 32-float column segment
        const float* __restrict__ fp = feat + (size_t)ch * (HH * WW) + row * WW + sg * 32;

        float u[32];
        #pragma unroll
        for (int i = 0; i < 8; ++i) {        // 8x global dwordx4; wave covers 8KB contiguous
            const float4 q = *(const float4*)&fp[i * 4];
            u[4 * i + 0] = q.x; u[4 * i + 1] = q.y;
            u[4 * i + 2] = q.z; u[4 * i + 3] = q.w;
        }
        #pragma unroll
        for (int i = 1; i < 32; ++i)         // serial register scan
            u[i] += u[i - 1];

        const float tot = u[31];             // cross-seg fixup within the quad
        const float t1 = __shfl_up(tot, 1, 64);
        const float t2 = __shfl_up(tot, 2, 64);
        const float t3 = __shfl_up(tot, 3, 64);
        float off = 0.0f;
        if (sg > 0) off += t1;
        if (sg > 1) off += t2;
        if (sg > 2) off += t3;

        float* rp = &S[row * LDW + sg * 32];
        #pragma unroll
        for (int i = 0; i < 8; ++i) {        // 8x ds_write_b128, bank-uniform
            float4 q;
            q.x = u[4 * i + 0] + off; q.y = u[4 * i + 1] + off;
            q.z = u[4 * i + 2] + off; q.w = u[4 * i + 3] + off;
            *(float4*)&rp[i * 4] = q;
        }
    }
    __syncthreads();   // the ONLY barrier; loads already consumed -> vmcnt drain free

    // ---- Phase 2: pooling — thread n = roi n for this channel ----
    {
        const int n  = tid;
        const int b  = ch / CCH;
        const int c  = ch - b * CCH;
        const int bi = (int)rois[n * 5 + 0];
        if (bi == b) {
            const float ss = 1.0f / (float)(*stride_p);
            const float x1 = rois[n * 5 + 1];
            const float y1 = rois[n * 5 + 2];
            const float x2 = rois[n * 5 + 3];
            const float y2 = rois[n * 5 + 4];

            // exact reference op order, fp32, no contraction
            float rsw = rintf(x1) * ss;
            float rsh = rintf(y1) * ss;
            float rew = (rintf(x2) + 1.0f) * ss;
            float reh = (rintf(y2) + 1.0f) * ss;
            float rwm = (rew - rsw) * 1.3f;
            float rhm = (reh - rsh) * 1.3f;
            const float swm = (rsw + rew) * 0.5f - rwm * 0.5f;
            const float shm = (rsh + reh) * 0.5f - rhm * 0.5f;
            rwm = fmaxf(rwm, 0.1f);
            rhm = fmaxf(rhm, 0.1f);
            const float bin_h = rhm / 7.0f;
            const float bin_w = rwm / 7.0f;
            const float dh = bin_h * 0.25f;
            const float dw = bin_w * 0.25f;

            const int d   = c / (GS * GS);
            const int rem = c - d * (GS * GS);
            const int pi  = rem / GS;
            const int pj  = rem - pi * GS;
            const float gi = (float)pi;
            const float gj = (float)pj;

            const int hs  = (int)fminf(fmaxf(floorf(shm + gi * bin_h - dh),          0.0f), 128.0f);
            const int he  = (int)fminf(fmaxf(ceilf (shm + (gi + 1.0f) * bin_h + dh), 0.0f), 128.0f);
            const int ws2 = (int)fminf(fmaxf(floorf(swm + gj * bin_w - dw),          0.0f), 128.0f);
            const int we  = (int)fminf(fmaxf(ceilf (swm + (gj + 1.0f) * bin_w + dw), 0.0f), 128.0f);

            const int area = (he - hs) * (we - ws2);
            float total = 0.0f;
            if (area > 0) {                  // he>hs and we>ws2
                if (ws2 > 0) {
                    for (int r = hs; r < he; ++r)
                        total += S[r * LDW + (we - 1)] - S[r * LDW + (ws2 - 1)];
                } else {
                    for (int r = hs; r < he; ++r)
                        total += S[r * LDW + (we - 1)];
                }
            }
            out[(size_t)n * CCH + c] = (area > 0) ? (total / (float)area) : 0.0f;
        }
    }
}

extern "C" void kernel_launch(void* const* d_in, const int* in_sizes, int n_in,
                              void* d_out, int out_size, void* d_ws, size_t ws_size,
                              hipStream_t stream)
{
    const float* rois     = (const float*)d_in[0];
    const float* feat     = (const float*)d_in[1];
    const int*   stride_p = (const int*)d_in[2];
    float*       out      = (float*)d_out;

    dim3 grid(NCH);    // 980 blocks: one per (batch, channel)
    dim3 block(512);
    hipLaunchKernelGGL(psroi_rowpfx, grid, block, 0, stream, rois, feat, stride_p, out);
}